// Round 8
// baseline (102.287 us; speedup 1.0000x reference)
//
#include <hip/hip_runtime.h>
#include <math.h>

#define N 512
#define DIM 128
#define TT 32            // D-tile edge (i and j) in gram kernel
#define PADS 132         // padded LDS row stride (floats), float4-aligned
#define GB (N / TT)      // 16x16 tile grid

// ws layout: D[N*N] | sums[N] | cnts[N] | done (int)

// Kernel A: D[i][j] = 18*max(0, 1 - dot(x_i,x_j)*rn_i*rn_j) by 32x32 tiles.
// 2x2 register micro-tile from LDS: 4 FMA per LDS b128 load (vs 1 in the
// one-anchor-per-block design — that intensity-1 GEMV shape was the ~20 us
// invariant across R4/R6/R7). Also zeros the done counter for kernel B.
__global__ void __launch_bounds__(256) gram_kernel(const float* __restrict__ x,
                                                   float* __restrict__ D,
                                                   int* __restrict__ done) {
    __shared__ float xi[TT * PADS];
    __shared__ float xj[TT * PADS];
    __shared__ float rnA[TT];
    __shared__ float rnB[TT];

    int bi = blockIdx.y, bj = blockIdx.x;
    int t = threadIdx.x;
    if (bi == 0 && bj == 0 && t == 0) *done = 0;

    // stage both 32x128 tiles, coalesced float4 (4 per thread per tile)
    const float4* srcA = (const float4*)(x + bi * TT * DIM);
    const float4* srcB = (const float4*)(x + bj * TT * DIM);
    #pragma unroll
    for (int k = 0; k < (TT * DIM / 4) / 256; ++k) {
        int e = t + k * 256;
        int r = e >> 5, c4 = e & 31;       // 32 float4 per row
        *((float4*)(xi + r * PADS + 4 * c4)) = srcA[e];
        *((float4*)(xj + r * PADS + 4 * c4)) = srcB[e];
    }
    __syncthreads();

    // inverse norms: 4 threads/row x 64 rows (32 from each tile), shfl reduce
    {
        int quart = t & 3, r = t >> 2;     // r: 0..63
        const float* base = (r < TT) ? (xi + r * PADS) : (xj + (r - TT) * PADS);
        const float4* a = (const float4*)(base + quart * 32);
        float s0 = 0.0f, s1 = 0.0f;
        #pragma unroll
        for (int q = 0; q < 8; q += 2) {
            float4 a0 = a[q], a1 = a[q + 1];
            s0 += a0.x * a0.x + a0.y * a0.y + a0.z * a0.z + a0.w * a0.w;
            s1 += a1.x * a1.x + a1.y * a1.y + a1.z * a1.z + a1.w * a1.w;
        }
        float ss = s0 + s1;
        ss += __shfl_xor(ss, 1, 64);
        ss += __shfl_xor(ss, 2, 64);
        if (quart == 0) {
            if (r < TT) rnA[r] = rsqrtf(ss);
            else        rnB[r - TT] = rsqrtf(ss);
        }
    }
    __syncthreads();

    // 2x2 micro-tile: thread (ty,tx) owns rows {2ty,2ty+1} x cols {2tx,2tx+1}
    int tx = t & 15, ty = t >> 4;
    int i0 = 2 * ty, i1 = i0 + 1, j0 = 2 * tx, j1 = j0 + 1;
    float acc00 = 0.0f, acc01 = 0.0f, acc10 = 0.0f, acc11 = 0.0f;
    const float4* A0 = (const float4*)(xi + i0 * PADS);
    const float4* A1 = (const float4*)(xi + i1 * PADS);
    const float4* B0 = (const float4*)(xj + j0 * PADS);
    const float4* B1 = (const float4*)(xj + j1 * PADS);
    #pragma unroll 8
    for (int k4 = 0; k4 < DIM / 4; ++k4) {
        float4 a0 = A0[k4], a1 = A1[k4], b0 = B0[k4], b1 = B1[k4];
        acc00 += a0.x * b0.x + a0.y * b0.y + a0.z * b0.z + a0.w * b0.w;
        acc01 += a0.x * b1.x + a0.y * b1.y + a0.z * b1.z + a0.w * b1.w;
        acc10 += a1.x * b0.x + a1.y * b0.y + a1.z * b0.z + a1.w * b0.w;
        acc11 += a1.x * b1.x + a1.y * b1.y + a1.z * b1.z + a1.w * b1.w;
    }
    float ri0 = rnA[i0], ri1 = rnA[i1], rj0 = rnB[j0], rj1 = rnB[j1];
    int gi0 = bi * TT + i0, gi1 = bi * TT + i1, gj = bj * TT + j0;
    float2 r0, r1;
    r0.x = 18.0f * fmaxf(0.0f, 1.0f - acc00 * ri0 * rj0);
    r0.y = 18.0f * fmaxf(0.0f, 1.0f - acc01 * ri0 * rj1);
    r1.x = 18.0f * fmaxf(0.0f, 1.0f - acc10 * ri1 * rj0);
    r1.y = 18.0f * fmaxf(0.0f, 1.0f - acc11 * ri1 * rj1);
    *((float2*)(D + gi0 * N + gj)) = r0;    // adjacent tx -> coalesced float2
    *((float2*)(D + gi1 * N + gj)) = r1;
}

// Kernel B: block per anchor i. Read D row i (2 KB, coalesced), compact
// same/diff lists, thread-per-k softplus (2 k/thread), per-block partial;
// the LAST block to finish (device-scope counter) reduces all partials ->
// out. (Separate same-address atomics per block cost ~10 us in R1; a cg
// grid.sync cost ~50 us in R5 — last-block-done avoids both.)
__global__ void __launch_bounds__(256) loss_kernel(const float* __restrict__ Dm,
                                                   const int* __restrict__ labels,
                                                   float* __restrict__ sums,
                                                   float* __restrict__ cnts,
                                                   int* __restrict__ done,
                                                   float* __restrict__ out) {
    __shared__ int   lab[N];
    __shared__ float sameD[N];
    __shared__ float diffD[N];
    __shared__ float red[4];
    __shared__ float rs[4], rc[4];
    __shared__ int   nsame, ndiff, lastFlag;

    int i = blockIdx.x, t = threadIdx.x;
    lab[t]       = labels[t];
    lab[t + 256] = labels[t + 256];
    if (t == 0) { nsame = 0; ndiff = 0; }
    float d0 = Dm[i * N + t];
    float d1 = Dm[i * N + t + 256];
    __syncthreads();

    int li = lab[i];
    {
        int j = t;
        if (lab[j] == li) {
            if (j != i) { int p = atomicAdd(&nsame, 1); sameD[p] = d0; }
        } else { int p = atomicAdd(&ndiff, 1); diffD[p] = d0; }
        j = t + 256;
        if (lab[j] == li) {
            if (j != i) { int p = atomicAdd(&nsame, 1); sameD[p] = d1; }
        } else { int p = atomicAdd(&ndiff, 1); diffD[p] = d1; }
    }
    __syncthreads();

    int ns = nsame, nd = ndiff;
    // softplus(s - k) = log(1 + e^s * e^-k); s in [0,36]: no fp32 overflow
    float ek0 = (t < nd)       ? __expf(-diffD[t])       : 0.0f;  // 0 -> log(1)=0
    float ek1 = (t + 256 < nd) ? __expf(-diffD[t + 256]) : 0.0f;
    float lsum = 0.0f;
    for (int js = 0; js < ns; ++js) {
        float es = __expf(sameD[js]);          // LDS broadcast read
        lsum += __logf(1.0f + es * ek0) + __logf(1.0f + es * ek1);
    }

    #pragma unroll
    for (int off = 32; off > 0; off >>= 1) lsum += __shfl_xor(lsum, off, 64);
    if ((t & 63) == 0) red[t >> 6] = lsum;
    __syncthreads();
    if (t == 0) {
        sums[i] = red[0] + red[1] + red[2] + red[3];
        cnts[i] = (float)(ns * nd);
    }
    __threadfence();                           // release partials (device scope)
    if (t == 0) lastFlag = (atomicAdd(done, 1) == N - 1) ? 1 : 0;
    __syncthreads();
    if (lastFlag) {
        __threadfence();                       // acquire others' partials
        float s = sums[t] + sums[t + 256];
        float c = cnts[t] + cnts[t + 256];
        #pragma unroll
        for (int off = 32; off > 0; off >>= 1) {
            s += __shfl_xor(s, off, 64);
            c += __shfl_xor(c, off, 64);
        }
        if ((t & 63) == 0) { rs[t >> 6] = s; rc[t >> 6] = c; }
        __syncthreads();
        if (t == 0)
            out[0] = (rs[0] + rs[1] + rs[2] + rs[3]) /
                     (rc[0] + rc[1] + rc[2] + rc[3]);
    }
}

extern "C" void kernel_launch(void* const* d_in, const int* in_sizes, int n_in,
                              void* d_out, int out_size, void* d_ws, size_t ws_size,
                              hipStream_t stream) {
    const float* x      = (const float*)d_in[0];
    const int*   labels = (const int*)d_in[1];
    float*       out    = (float*)d_out;

    float* Dm   = (float*)d_ws;       // 512*512 floats = 1 MB
    float* sums = Dm + N * N;         // 512 floats
    float* cnts = sums + N;           // 512 floats
    int*   done = (int*)(cnts + N);   // zeroed by gram_kernel each call

    gram_kernel<<<dim3(GB, GB), 256, 0, stream>>>(x, Dm, done);
    loss_kernel<<<N, 256, 0, stream>>>(Dm, labels, sums, cnts, done, out);
}

// Round 9
// 65.867 us; speedup vs baseline: 1.5529x; 1.5529x over previous
//
#include <hip/hip_runtime.h>
#include <math.h>

#define N 512
#define DIM 128
#define TT 32            // D-tile edge (i and j) in gram kernel
#define PADS 132         // padded LDS row stride (floats), float4-aligned
#define GB (N / TT)      // 16x16 tile grid

// ws layout: D[N*N] | sums[N] | cnts[N]

// Kernel A: D[i][j] = 18*max(0, 1 - dot(x_i,x_j)*rn_i*rn_j) by 32x32 tiles.
// 2x2 register micro-tile from LDS: 4 FMA per LDS b128 load. (GEMV-shaped
// one-anchor-per-block was the ~20 us invariant across R4/R6/R7; this runs
// ~4 us.)
__global__ void __launch_bounds__(256) gram_kernel(const float* __restrict__ x,
                                                   float* __restrict__ D) {
    __shared__ float xi[TT * PADS];
    __shared__ float xj[TT * PADS];
    __shared__ float rnA[TT];
    __shared__ float rnB[TT];

    int bi = blockIdx.y, bj = blockIdx.x;
    int t = threadIdx.x;

    // stage both 32x128 tiles, coalesced float4 (4 per thread per tile)
    const float4* srcA = (const float4*)(x + bi * TT * DIM);
    const float4* srcB = (const float4*)(x + bj * TT * DIM);
    #pragma unroll
    for (int k = 0; k < (TT * DIM / 4) / 256; ++k) {
        int e = t + k * 256;
        int r = e >> 5, c4 = e & 31;       // 32 float4 per row
        *((float4*)(xi + r * PADS + 4 * c4)) = srcA[e];
        *((float4*)(xj + r * PADS + 4 * c4)) = srcB[e];
    }
    __syncthreads();

    // inverse norms: 4 threads/row x 64 rows (32 from each tile), shfl reduce
    {
        int quart = t & 3, r = t >> 2;     // r: 0..63
        const float* base = (r < TT) ? (xi + r * PADS) : (xj + (r - TT) * PADS);
        const float4* a = (const float4*)(base + quart * 32);
        float s0 = 0.0f, s1 = 0.0f;
        #pragma unroll
        for (int q = 0; q < 8; q += 2) {
            float4 a0 = a[q], a1 = a[q + 1];
            s0 += a0.x * a0.x + a0.y * a0.y + a0.z * a0.z + a0.w * a0.w;
            s1 += a1.x * a1.x + a1.y * a1.y + a1.z * a1.z + a1.w * a1.w;
        }
        float ss = s0 + s1;
        ss += __shfl_xor(ss, 1, 64);
        ss += __shfl_xor(ss, 2, 64);
        if (quart == 0) {
            if (r < TT) rnA[r] = rsqrtf(ss);
            else        rnB[r - TT] = rsqrtf(ss);
        }
    }
    __syncthreads();

    // 2x2 micro-tile: thread (ty,tx) owns rows {2ty,2ty+1} x cols {2tx,2tx+1}
    int tx = t & 15, ty = t >> 4;
    int i0 = 2 * ty, i1 = i0 + 1, j0 = 2 * tx, j1 = j0 + 1;
    float acc00 = 0.0f, acc01 = 0.0f, acc10 = 0.0f, acc11 = 0.0f;
    const float4* A0 = (const float4*)(xi + i0 * PADS);
    const float4* A1 = (const float4*)(xi + i1 * PADS);
    const float4* B0 = (const float4*)(xj + j0 * PADS);
    const float4* B1 = (const float4*)(xj + j1 * PADS);
    #pragma unroll 8
    for (int k4 = 0; k4 < DIM / 4; ++k4) {
        float4 a0 = A0[k4], a1 = A1[k4], b0 = B0[k4], b1 = B1[k4];
        acc00 += a0.x * b0.x + a0.y * b0.y + a0.z * b0.z + a0.w * b0.w;
        acc01 += a0.x * b1.x + a0.y * b1.y + a0.z * b1.z + a0.w * b1.w;
        acc10 += a1.x * b0.x + a1.y * b0.y + a1.z * b0.z + a1.w * b0.w;
        acc11 += a1.x * b1.x + a1.y * b1.y + a1.z * b1.z + a1.w * b1.w;
    }
    float ri0 = rnA[i0], ri1 = rnA[i1], rj0 = rnB[j0], rj1 = rnB[j1];
    int gi0 = bi * TT + i0, gi1 = bi * TT + i1, gj = bj * TT + j0;
    float2 r0, r1;
    r0.x = 18.0f * fmaxf(0.0f, 1.0f - acc00 * ri0 * rj0);
    r0.y = 18.0f * fmaxf(0.0f, 1.0f - acc01 * ri0 * rj1);
    r1.x = 18.0f * fmaxf(0.0f, 1.0f - acc10 * ri1 * rj0);
    r1.y = 18.0f * fmaxf(0.0f, 1.0f - acc11 * ri1 * rj1);
    *((float2*)(D + gi0 * N + gj)) = r0;    // adjacent tx -> coalesced float2
    *((float2*)(D + gi1 * N + gj)) = r1;
}

// Kernel B: block per anchor i. Read D row i (2 KB, coalesced), compact
// same/diff lists, thread-per-k softplus (2 k/thread), per-block partial.
// NO grid-wide rendezvous: cg.sync (R5, +50us), same-address device atomics
// (R1, ~36ns each serialized) and fence-heavy last-block-done (R8, +45us)
// all lose to a 1us kernel boundary on this chip.
__global__ void __launch_bounds__(256) loss_kernel(const float* __restrict__ Dm,
                                                   const int* __restrict__ labels,
                                                   float* __restrict__ sums,
                                                   float* __restrict__ cnts) {
    __shared__ int   lab[N];
    __shared__ float sameD[N];
    __shared__ float diffD[N];
    __shared__ float red[4];
    __shared__ int   nsame, ndiff;

    int i = blockIdx.x, t = threadIdx.x;
    lab[t]       = labels[t];
    lab[t + 256] = labels[t + 256];
    if (t == 0) { nsame = 0; ndiff = 0; }
    float d0 = Dm[i * N + t];
    float d1 = Dm[i * N + t + 256];
    __syncthreads();

    int li = lab[i];
    {
        int j = t;
        if (lab[j] == li) {
            if (j != i) { int p = atomicAdd(&nsame, 1); sameD[p] = d0; }
        } else { int p = atomicAdd(&ndiff, 1); diffD[p] = d0; }
        j = t + 256;
        if (lab[j] == li) {
            if (j != i) { int p = atomicAdd(&nsame, 1); sameD[p] = d1; }
        } else { int p = atomicAdd(&ndiff, 1); diffD[p] = d1; }
    }
    __syncthreads();

    int ns = nsame, nd = ndiff;
    // softplus(s - k) = log(1 + e^s * e^-k); s in [0,36]: no fp32 overflow
    float ek0 = (t < nd)       ? __expf(-diffD[t])       : 0.0f;  // 0 -> log(1)=0
    float ek1 = (t + 256 < nd) ? __expf(-diffD[t + 256]) : 0.0f;
    float lsum = 0.0f;
    for (int js = 0; js < ns; ++js) {
        float es = __expf(sameD[js]);          // LDS broadcast read
        lsum += __logf(1.0f + es * ek0) + __logf(1.0f + es * ek1);
    }

    #pragma unroll
    for (int off = 32; off > 0; off >>= 1) lsum += __shfl_xor(lsum, off, 64);
    if ((t & 63) == 0) red[t >> 6] = lsum;
    __syncthreads();
    if (t == 0) {
        sums[i] = red[0] + red[1] + red[2] + red[3];
        cnts[i] = (float)(ns * nd);
    }
}

// Kernel C: reduce the 512 per-block partials (contention-free).
__global__ void __launch_bounds__(256) finalize_kernel(const float* __restrict__ sums,
                                                       const float* __restrict__ cnts,
                                                       float* __restrict__ out) {
    __shared__ float2 red[256];
    int t = threadIdx.x;
    float2 v;
    v.x = sums[t] + sums[t + 256];
    v.y = cnts[t] + cnts[t + 256];
    red[t] = v;
    __syncthreads();
    #pragma unroll
    for (int s = 128; s > 0; s >>= 1) {
        if (t < s) {
            red[t].x += red[t + s].x;
            red[t].y += red[t + s].y;
        }
        __syncthreads();
    }
    if (t == 0) out[0] = red[0].x / red[0].y;
}

extern "C" void kernel_launch(void* const* d_in, const int* in_sizes, int n_in,
                              void* d_out, int out_size, void* d_ws, size_t ws_size,
                              hipStream_t stream) {
    const float* x      = (const float*)d_in[0];
    const int*   labels = (const int*)d_in[1];
    float*       out    = (float*)d_out;

    float* Dm   = (float*)d_ws;       // 512*512 floats = 1 MB
    float* sums = Dm + N * N;         // 512 floats
    float* cnts = sums + N;           // 512 floats

    gram_kernel<<<dim3(GB, GB), 256, 0, stream>>>(x, Dm);
    loss_kernel<<<N, 256, 0, stream>>>(Dm, labels, sums, cnts);
    finalize_kernel<<<1, 256, 0, stream>>>(sums, cnts, out);
}

// Round 10
// 65.430 us; speedup vs baseline: 1.5633x; 1.0067x over previous
//
#include <hip/hip_runtime.h>
#include <math.h>

#define N 512
#define DIM 128
#define TT 32            // D-tile edge (i and j) in gram kernel
#define PADS 132         // padded LDS row stride (floats), float4-aligned
#define NTRI (16 * 17 / 2)   // 136 lower-triangle tile blocks

// ws layout: D[N*N] | sums[N] | cnts[N]

// Kernel A: D[i][j] = 18*max(0, 1 - dot(x_i,x_j)*rn_i*rn_j), SYMMETRIC:
// triangular grid of 136 blocks; off-diagonal tiles are computed once and
// written twice (direct coalesced + LDS-transposed mirror, reusing the xi
// staging buffer). 2x2 register micro-tile: 4 FMA per LDS b128 load.
__global__ void __launch_bounds__(256) gram_kernel(const float* __restrict__ x,
                                                   float* __restrict__ D) {
    __shared__ float xi[TT * PADS];
    __shared__ float xj[TT * PADS];
    __shared__ float rnA[TT];
    __shared__ float rnB[TT];

    int t = threadIdx.x;

    // linear block index -> (bi, bj), bj <= bi (lower triangle)
    int b = blockIdx.x;
    int bi = (int)((sqrtf(8.0f * (float)b + 1.0f) - 1.0f) * 0.5f);
    while ((bi + 1) * (bi + 2) / 2 <= b) ++bi;   // float fixup
    while (bi * (bi + 1) / 2 > b) --bi;
    int bj = b - bi * (bi + 1) / 2;

    // stage both 32x128 tiles, coalesced float4 (4 per thread per tile)
    const float4* srcA = (const float4*)(x + bi * TT * DIM);
    const float4* srcB = (const float4*)(x + bj * TT * DIM);
    #pragma unroll
    for (int k = 0; k < (TT * DIM / 4) / 256; ++k) {
        int e = t + k * 256;
        int r = e >> 5, c4 = e & 31;       // 32 float4 per row
        *((float4*)(xi + r * PADS + 4 * c4)) = srcA[e];
        *((float4*)(xj + r * PADS + 4 * c4)) = srcB[e];
    }
    __syncthreads();

    // inverse norms: 4 threads/row x 64 rows (32 from each tile), shfl reduce
    {
        int quart = t & 3, r = t >> 2;     // r: 0..63
        const float* base = (r < TT) ? (xi + r * PADS) : (xj + (r - TT) * PADS);
        const float4* a = (const float4*)(base + quart * 32);
        float s0 = 0.0f, s1 = 0.0f;
        #pragma unroll
        for (int q = 0; q < 8; q += 2) {
            float4 a0 = a[q], a1 = a[q + 1];
            s0 += a0.x * a0.x + a0.y * a0.y + a0.z * a0.z + a0.w * a0.w;
            s1 += a1.x * a1.x + a1.y * a1.y + a1.z * a1.z + a1.w * a1.w;
        }
        float ss = s0 + s1;
        ss += __shfl_xor(ss, 1, 64);
        ss += __shfl_xor(ss, 2, 64);
        if (quart == 0) {
            if (r < TT) rnA[r] = rsqrtf(ss);
            else        rnB[r - TT] = rsqrtf(ss);
        }
    }
    __syncthreads();

    // 2x2 micro-tile: thread (ty,tx) owns rows {2ty,2ty+1} x cols {2tx,2tx+1}
    int tx = t & 15, ty = t >> 4;
    int i0 = 2 * ty, i1 = i0 + 1, j0 = 2 * tx, j1 = j0 + 1;
    float acc00 = 0.0f, acc01 = 0.0f, acc10 = 0.0f, acc11 = 0.0f;
    const float4* A0 = (const float4*)(xi + i0 * PADS);
    const float4* A1 = (const float4*)(xi + i1 * PADS);
    const float4* B0 = (const float4*)(xj + j0 * PADS);
    const float4* B1 = (const float4*)(xj + j1 * PADS);
    #pragma unroll 8
    for (int k4 = 0; k4 < DIM / 4; ++k4) {
        float4 a0 = A0[k4], a1 = A1[k4], b0 = B0[k4], b1 = B1[k4];
        acc00 += a0.x * b0.x + a0.y * b0.y + a0.z * b0.z + a0.w * b0.w;
        acc01 += a0.x * b1.x + a0.y * b1.y + a0.z * b1.z + a0.w * b1.w;
        acc10 += a1.x * b0.x + a1.y * b0.y + a1.z * b0.z + a1.w * b0.w;
        acc11 += a1.x * b1.x + a1.y * b1.y + a1.z * b1.z + a1.w * b1.w;
    }
    float ri0 = rnA[i0], ri1 = rnA[i1], rj0 = rnB[j0], rj1 = rnB[j1];
    // T[a][b] = D value at global (bi*32+a, bj*32+b)
    float t00 = 18.0f * fmaxf(0.0f, 1.0f - acc00 * ri0 * rj0);
    float t01 = 18.0f * fmaxf(0.0f, 1.0f - acc01 * ri0 * rj1);
    float t10 = 18.0f * fmaxf(0.0f, 1.0f - acc10 * ri1 * rj0);
    float t11 = 18.0f * fmaxf(0.0f, 1.0f - acc11 * ri1 * rj1);

    // direct write (coalesced float2 across tx)
    {
        int gi0 = bi * TT + i0, gi1 = bi * TT + i1, gj = bj * TT + j0;
        float2 r0 = {t00, t01}, r1 = {t10, t11};
        *((float2*)(D + gi0 * N + gj)) = r0;
        *((float2*)(D + gi1 * N + gj)) = r1;
    }

    if (bi != bj) {
        // mirror write via LDS transpose; xi is dead now, reuse as Tt[32][33]
        __syncthreads();                    // everyone done reading xi
        float* Tt = xi;                     // Tt[a][b] = T[b][a], stride 33
        Tt[j0 * 33 + i0] = t00;
        Tt[j1 * 33 + i0] = t01;
        Tt[j0 * 33 + i1] = t10;
        Tt[j1 * 33 + i1] = t11;
        __syncthreads();
        int ga0 = bj * TT + i0, ga1 = bj * TT + i1, gb = bi * TT + j0;
        float2 m0 = {Tt[i0 * 33 + j0], Tt[i0 * 33 + j1]};
        float2 m1 = {Tt[i1 * 33 + j0], Tt[i1 * 33 + j1]};
        *((float2*)(D + ga0 * N + gb)) = m0;
        *((float2*)(D + ga1 * N + gb)) = m1;
    }
}

// Kernel B: block per anchor i. Read D row i (2 KB, coalesced), compact
// same/diff lists, thread-per-k softplus (2 k/thread), per-block partial.
// NO grid-wide rendezvous: cg.sync (R5, +50us), same-address device atomics
// (R1, ~18us) and fence-heavy last-block-done (R8, +45us) all lose to a
// ~1us kernel boundary on this chip.
__global__ void __launch_bounds__(256) loss_kernel(const float* __restrict__ Dm,
                                                   const int* __restrict__ labels,
                                                   float* __restrict__ sums,
                                                   float* __restrict__ cnts) {
    __shared__ int   lab[N];
    __shared__ float sameD[N];
    __shared__ float diffD[N];
    __shared__ float red[4];
    __shared__ int   nsame, ndiff;

    int i = blockIdx.x, t = threadIdx.x;
    lab[t]       = labels[t];
    lab[t + 256] = labels[t + 256];
    if (t == 0) { nsame = 0; ndiff = 0; }
    float d0 = Dm[i * N + t];
    float d1 = Dm[i * N + t + 256];
    __syncthreads();

    int li = lab[i];
    {
        int j = t;
        if (lab[j] == li) {
            if (j != i) { int p = atomicAdd(&nsame, 1); sameD[p] = d0; }
        } else { int p = atomicAdd(&ndiff, 1); diffD[p] = d0; }
        j = t + 256;
        if (lab[j] == li) {
            if (j != i) { int p = atomicAdd(&nsame, 1); sameD[p] = d1; }
        } else { int p = atomicAdd(&ndiff, 1); diffD[p] = d1; }
    }
    __syncthreads();

    int ns = nsame, nd = ndiff;
    // softplus(s - k) = log(1 + e^s * e^-k); s in [0,36]: no fp32 overflow
    float ek0 = (t < nd)       ? __expf(-diffD[t])       : 0.0f;  // 0 -> log(1)=0
    float ek1 = (t + 256 < nd) ? __expf(-diffD[t + 256]) : 0.0f;
    float lsum = 0.0f;
    for (int js = 0; js < ns; ++js) {
        float es = __expf(sameD[js]);          // LDS broadcast read
        lsum += __logf(1.0f + es * ek0) + __logf(1.0f + es * ek1);
    }

    #pragma unroll
    for (int off = 32; off > 0; off >>= 1) lsum += __shfl_xor(lsum, off, 64);
    if ((t & 63) == 0) red[t >> 6] = lsum;
    __syncthreads();
    if (t == 0) {
        sums[i] = red[0] + red[1] + red[2] + red[3];
        cnts[i] = (float)(ns * nd);
    }
}

// Kernel C: reduce the 512 per-block partials (contention-free).
__global__ void __launch_bounds__(256) finalize_kernel(const float* __restrict__ sums,
                                                       const float* __restrict__ cnts,
                                                       float* __restrict__ out) {
    __shared__ float2 red[256];
    int t = threadIdx.x;
    float2 v;
    v.x = sums[t] + sums[t + 256];
    v.y = cnts[t] + cnts[t + 256];
    red[t] = v;
    __syncthreads();
    #pragma unroll
    for (int s = 128; s > 0; s >>= 1) {
        if (t < s) {
            red[t].x += red[t + s].x;
            red[t].y += red[t + s].y;
        }
        __syncthreads();
    }
    if (t == 0) out[0] = red[0].x / red[0].y;
}

extern "C" void kernel_launch(void* const* d_in, const int* in_sizes, int n_in,
                              void* d_out, int out_size, void* d_ws, size_t ws_size,
                              hipStream_t stream) {
    const float* x      = (const float*)d_in[0];
    const int*   labels = (const int*)d_in[1];
    float*       out    = (float*)d_out;

    float* Dm   = (float*)d_ws;       // 512*512 floats = 1 MB
    float* sums = Dm + N * N;         // 512 floats
    float* cnts = sums + N;           // 512 floats

    gram_kernel<<<NTRI, 256, 0, stream>>>(x, Dm);
    loss_kernel<<<N, 256, 0, stream>>>(Dm, labels, sums, cnts);
    finalize_kernel<<<1, 256, 0, stream>>>(sums, cnts, out);
}